// Round 1
// baseline (733.947 us; speedup 1.0000x reference)
//
#include <hip/hip_runtime.h>
#include <math.h>

// BalancedFrequencyAttention: analytic collapse.
// gap[b,c] = (0.6/sqrt(480) * sum(x[b,c,:,:]) + 0.4 * Q[b,c]) / (200*sqrt(240))
// where Q = sum over rows h in [80,200) of dot(x[b,c,h,:], Wcls[(h-80)%3])
//   Wcls0 = D[80,:]+D[320,:], Wcls1 = D[160,:]+D[400,:], Wcls2 = D[240,:]
//   (D = DCT-II matrix of size 480; only 5 frequencies survive the
//    reshape+column-mean, since mean_n D2[k,n]==0 for k>=1)
// att = sigmoid(gap @ w1.T @ w2.T); out = x * att[b,c]

namespace {

constexpr int Hh     = 200;
constexpr int Ww     = 480;
constexpr int PLANE  = Hh * Ww;     // 96000 floats per (b,c)
constexpr int NBC    = 8 * 128;     // 1024 planes
constexpr int ROW4   = Ww / 4;      // 120 float4 per row
constexpr int CHUNK4 = (PLANE / 4) / 4;  // 6000 float4 per y-chunk (4 chunks)

__global__ __launch_bounds__(256) void gap_kernel(const float* __restrict__ x,
                                                  float* __restrict__ gap) {
    __shared__ float Wt[3][Ww];
    __shared__ float redp[4], redq[4];
    const int t = threadIdx.x;

    // Build the 3 combined DCT weight rows. Integer phase reduction keeps
    // __cosf args in [0, 2pi) for accuracy.
    const float s   = 0.06454972243679028f;   // sqrt(2/480)
    const float c2a = (float)(M_PI / 960.0);
    for (int n = t; n < Ww; n += 256) {
        int tn = 2 * n + 1;
        float a80  = (float)((tn * 80)  % 1920) * c2a;
        float a160 = (float)((tn * 160) % 1920) * c2a;
        float a240 = (float)((tn * 240) % 1920) * c2a;
        float a320 = (float)((tn * 320) % 1920) * c2a;
        float a400 = (float)((tn * 400) % 1920) * c2a;
        Wt[0][n] = s * (__cosf(a80)  + __cosf(a320));
        Wt[1][n] = s * (__cosf(a160) + __cosf(a400));
        Wt[2][n] = s * __cosf(a240);
    }
    __syncthreads();

    const int wave = t >> 6, lane = t & 63;
    const float4* xp = (const float4*)(x + (size_t)blockIdx.x * PLANE);
    float p = 0.f, q = 0.f;
    // 4 waves stride over 200 rows; each row = 120 float4 (lane + lane+64).
    for (int h = wave; h < Hh; h += 4) {
        const float4* row = xp + h * ROW4;
        float4 v = row[lane];
        p += (v.x + v.y) + (v.z + v.w);
        float4 v2;
        const bool has2 = (lane < ROW4 - 64);   // 56 lanes take 2nd vec
        if (has2) {
            v2 = row[lane + 64];
            p += (v2.x + v2.y) + (v2.z + v2.w);
        }
        if (h >= 80) {
            const float4* wrow = (const float4*)Wt[(h - 80) % 3];
            float4 wv = wrow[lane];
            q += v.x * wv.x + v.y * wv.y + v.z * wv.z + v.w * wv.w;
            if (has2) {
                float4 wv2 = wrow[lane + 64];
                q += v2.x * wv2.x + v2.y * wv2.y + v2.z * wv2.z + v2.w * wv2.w;
            }
        }
    }
    #pragma unroll
    for (int o = 32; o > 0; o >>= 1) {
        p += __shfl_down(p, o);
        q += __shfl_down(q, o);
    }
    if (lane == 0) { redp[wave] = p; redq[wave] = q; }
    __syncthreads();
    if (t == 0) {
        float P = (redp[0] + redp[1]) + (redp[2] + redp[3]);
        float Q = (redq[0] + redq[1]) + (redq[2] + redq[3]);
        float total = 0.02738612787525831f * P + 0.4f * Q;  // 0.6/sqrt(480)
        gap[blockIdx.x] = total * 3.227486121839514e-4f;    // 1/(200*sqrt(240))
    }
}

__global__ __launch_bounds__(256) void att_kernel(const float* __restrict__ gap,
                                                  const float* __restrict__ w1,
                                                  const float* __restrict__ w2,
                                                  float* __restrict__ att) {
    __shared__ float g[1024];
    __shared__ float t1[8][32];
    const int t = threadIdx.x;
    for (int i = t; i < 1024; i += 256) g[i] = gap[i];
    __syncthreads();
    // t1[b,j] = sum_c gap[b,c] * w1[j,c]   (w1 is (32,128) row-major)
    {
        const int b = t >> 5, j = t & 31;
        float acc = 0.f;
        #pragma unroll 8
        for (int c = 0; c < 128; c++) acc += g[b * 128 + c] * w1[j * 128 + c];
        t1[b][j] = acc;
    }
    __syncthreads();
    // att[b,c] = sigmoid(sum_j t1[b,j] * w2[c,j])  (w2 is (128,32) row-major)
    for (int i = t; i < 1024; i += 256) {
        const int b = i >> 7, c = i & 127;
        float acc = 0.f;
        #pragma unroll
        for (int j = 0; j < 32; j++) acc += t1[b][j] * w2[c * 32 + j];
        att[i] = 1.f / (1.f + __expf(-acc));
    }
}

__global__ __launch_bounds__(256) void scale_kernel(const float* __restrict__ x,
                                                    const float* __restrict__ att,
                                                    float* __restrict__ out) {
    const int bc = blockIdx.x;                 // (b*128+c) plane
    const float a = att[bc];
    const float4* xp = (const float4*)(x + (size_t)bc * PLANE);
    float4*       op = (float4*)(out + (size_t)bc * PLANE);
    const int start = blockIdx.y * CHUNK4;
    const int end   = start + CHUNK4;
    for (int i = start + threadIdx.x; i < end; i += 256) {
        float4 v = xp[i];
        v.x *= a; v.y *= a; v.z *= a; v.w *= a;
        op[i] = v;
    }
}

}  // namespace

extern "C" void kernel_launch(void* const* d_in, const int* in_sizes, int n_in,
                              void* d_out, int out_size, void* d_ws, size_t ws_size,
                              hipStream_t stream) {
    const float* x  = (const float*)d_in[0];
    const float* w1 = (const float*)d_in[1];
    const float* w2 = (const float*)d_in[2];
    float* out = (float*)d_out;
    float* gap = (float*)d_ws;        // 1024 floats
    float* att = gap + 1024;          // 1024 floats

    gap_kernel<<<NBC, 256, 0, stream>>>(x, gap);
    att_kernel<<<1, 256, 0, stream>>>(gap, w1, w2, att);
    scale_kernel<<<dim3(NBC, 4), 256, 0, stream>>>(x, att, out);
}

// Round 2
// 715.669 us; speedup vs baseline: 1.0255x; 1.0255x over previous
//
#include <hip/hip_runtime.h>
#include <math.h>

// BalancedFrequencyAttention: analytic collapse (verified round 1, absmax 7.8e-3).
// gap[b,c] = (0.6/sqrt(480) * P + 0.4 * Q) / (200*sqrt(240))
//   P = sum(x[b,c,:,:]),  Q = sum_{h>=80} dot(x[b,c,h,:], Wcls[(h-80)%3])
//   Wcls0 = D[80,:]+D[320,:], Wcls1 = D[160,:]+D[400,:], Wcls2 = D[240,:]
// att = sigmoid(gap @ w1.T @ w2.T); out = x * att[b,c]
//
// R2 changes: gap split 2 blocks/plane + 4-row unroll (8 loads in flight/wave);
// att one block per batch; scale 4x unrolled + reverse plane order for L3 reuse.

namespace {

constexpr int Hh    = 200;
constexpr int Ww    = 480;
constexpr int PLANE = Hh * Ww;        // 96000 floats / plane
constexpr int NBC   = 8 * 128;        // 1024 planes
constexpr int ROW4  = Ww / 4;         // 120 float4 / row

__global__ __launch_bounds__(256, 4) void gap_kernel(const float* __restrict__ x,
                                                     float2* __restrict__ pq) {
    __shared__ __align__(16) float Wt[4][Ww];
    __shared__ float redp[4], redq[4];
    const int t = threadIdx.x;

    const float s   = 0.06454972243679028f;   // sqrt(2/480)
    const float c2a = (float)(M_PI / 960.0);
    for (int n = t; n < Ww; n += 256) {
        int tn = 2 * n + 1;
        Wt[0][n] = s * (__cosf((float)((tn *  80) % 1920) * c2a) +
                        __cosf((float)((tn * 320) % 1920) * c2a));
        Wt[1][n] = s * (__cosf((float)((tn * 160) % 1920) * c2a) +
                        __cosf((float)((tn * 400) % 1920) * c2a));
        Wt[2][n] = s *  __cosf((float)((tn * 240) % 1920) * c2a);
        Wt[3][n] = 0.f;                       // rows h<80: zero weight
    }
    __syncthreads();

    const int wave = t >> 6, lane = t & 63;
    const int bc = blockIdx.x >> 1, part = blockIdx.x & 1;
    const int r0 = part * 100;                // rows [r0, r0+100)
    const float4* xp = (const float4*)(x + (size_t)bc * PLANE);
    const bool has2 = lane < (ROW4 - 64);     // 56 of 64 lanes take 2nd vec
    const float4 z4 = {0.f, 0.f, 0.f, 0.f};

    float p = 0.f, q = 0.f;
    // 6 tiles of 16 rows (4 consecutive rows per wave, unrolled) + 4-row tail.
    for (int tile = 0; tile < 6; tile++) {
        const int hb = r0 + tile * 16 + wave * 4;
        #pragma unroll
        for (int rr = 0; rr < 4; rr++) {
            const int h = hb + rr;
            const float4* row = xp + h * ROW4;
            float4 v  = row[lane];
            float4 v2 = has2 ? row[lane + 64] : z4;
            const int cls = (h < 80) ? 3 : (h - 80) % 3;   // wave-uniform
            const float4* wrow = (const float4*)Wt[cls];
            float4 wv  = wrow[lane];
            float4 wv2 = has2 ? wrow[lane + 64] : z4;
            p += (v.x + v.y) + (v.z + v.w) + (v2.x + v2.y) + (v2.z + v2.w);
            q += v.x * wv.x + v.y * wv.y + v.z * wv.z + v.w * wv.w
               + v2.x * wv2.x + v2.y * wv2.y + v2.z * wv2.z + v2.w * wv2.w;
        }
    }
    {   // tail: rows r0+96 .. r0+99, one per wave
        const int h = r0 + 96 + wave;
        const float4* row = xp + h * ROW4;
        float4 v  = row[lane];
        float4 v2 = has2 ? row[lane + 64] : z4;
        const int cls = (h < 80) ? 3 : (h - 80) % 3;
        const float4* wrow = (const float4*)Wt[cls];
        float4 wv  = wrow[lane];
        float4 wv2 = has2 ? wrow[lane + 64] : z4;
        p += (v.x + v.y) + (v.z + v.w) + (v2.x + v2.y) + (v2.z + v2.w);
        q += v.x * wv.x + v.y * wv.y + v.z * wv.z + v.w * wv.w
           + v2.x * wv2.x + v2.y * wv2.y + v2.z * wv2.z + v2.w * wv2.w;
    }

    #pragma unroll
    for (int o = 32; o > 0; o >>= 1) {
        p += __shfl_down(p, o);
        q += __shfl_down(q, o);
    }
    if (lane == 0) { redp[wave] = p; redq[wave] = q; }
    __syncthreads();
    if (t == 0) {
        float P = (redp[0] + redp[1]) + (redp[2] + redp[3]);
        float Q = (redq[0] + redq[1]) + (redq[2] + redq[3]);
        pq[blockIdx.x] = make_float2(P, Q);
    }
}

__global__ __launch_bounds__(256) void att_kernel(const float2* __restrict__ pq,
                                                  const float* __restrict__ w1,
                                                  const float* __restrict__ w2,
                                                  float* __restrict__ att) {
    __shared__ float g[128];
    __shared__ float t1[32];
    const int b = blockIdx.x, t = threadIdx.x;
    if (t < 128) {
        float2 a0 = pq[(b * 128 + t) * 2 + 0];
        float2 a1 = pq[(b * 128 + t) * 2 + 1];
        float P = a0.x + a1.x, Q = a0.y + a1.y;
        // (0.6/sqrt(480))*P + 0.4*Q, then / (200*sqrt(240))
        g[t] = (0.02738612787525831f * P + 0.4f * Q) * 3.227486121839514e-4f;
    }
    __syncthreads();
    if (t < 32) {
        float acc = 0.f;
        #pragma unroll
        for (int c = 0; c < 128; c++) acc += g[c] * w1[t * 128 + c];
        t1[t] = acc;
    }
    __syncthreads();
    if (t < 128) {
        float acc = 0.f;
        #pragma unroll
        for (int j = 0; j < 32; j++) acc += t1[j] * w2[t * 32 + j];
        att[b * 128 + t] = 1.f / (1.f + __expf(-acc));
    }
}

__global__ __launch_bounds__(256) void scale_kernel(const float* __restrict__ x,
                                                    const float* __restrict__ att,
                                                    float* __restrict__ out) {
    // Reverse plane order: gap read planes ascending, so the highest-bc
    // planes are the ones still resident in the 256 MB Infinity Cache.
    const int bc = (NBC - 1) - (int)blockIdx.x;
    const float a = att[bc];
    const float4* __restrict__ xp = (const float4*)(x   + (size_t)bc * PLANE);
    float4* __restrict__       op = (float4*)      (out + (size_t)bc * PLANE);
    const int start = blockIdx.y * 6000;      // PLANE/4 = 24000 f4, 4 chunks
    const int end   = start + 6000;
    int i = start + (int)threadIdx.x;
    for (; i + 768 < end; i += 1024) {
        float4 v0 = xp[i], v1 = xp[i + 256], v2 = xp[i + 512], v3 = xp[i + 768];
        v0.x *= a; v0.y *= a; v0.z *= a; v0.w *= a;
        v1.x *= a; v1.y *= a; v1.z *= a; v1.w *= a;
        v2.x *= a; v2.y *= a; v2.z *= a; v2.w *= a;
        v3.x *= a; v3.y *= a; v3.z *= a; v3.w *= a;
        op[i] = v0; op[i + 256] = v1; op[i + 512] = v2; op[i + 768] = v3;
    }
    for (; i < end; i += 256) {
        float4 v = xp[i];
        v.x *= a; v.y *= a; v.z *= a; v.w *= a;
        op[i] = v;
    }
}

}  // namespace

extern "C" void kernel_launch(void* const* d_in, const int* in_sizes, int n_in,
                              void* d_out, int out_size, void* d_ws, size_t ws_size,
                              hipStream_t stream) {
    const float* x  = (const float*)d_in[0];
    const float* w1 = (const float*)d_in[1];
    const float* w2 = (const float*)d_in[2];
    float* out = (float*)d_out;
    float2* pq = (float2*)d_ws;               // 2048 float2 partials
    float* att = (float*)d_ws + 4096;         // 1024 floats

    gap_kernel<<<NBC * 2, 256, 0, stream>>>(x, pq);
    att_kernel<<<8, 256, 0, stream>>>(pq, w1, w2, att);
    scale_kernel<<<dim3(NBC, 4), 256, 0, stream>>>(x, att, out);
}